// Round 12
// baseline (34.097 us; speedup 1.0000x reference)
//
#include <hip/hip_runtime.h>
#include <cfloat>
#include <cmath>

#define NB 64
#define NQ 900
#define NM 64
#define NC 4
#define THREADS 256
#define NCT 225   // col-threads: thread t (t<225) owns cols [4t, 4t+4)
#define MAGIC 0x5A17C0DEu

// Apply X to the 4 per-thread column slots
#define S4_LIST(X) X(0) X(1) X(2) X(3)

__device__ __forceinline__ unsigned int uminu(unsigned int a, unsigned int b) {
    return a < b ? a : b;
}

__device__ __forceinline__ float readlane_f(float v, int l) {
    return __uint_as_float(
        (unsigned)__builtin_amdgcn_readlane(__float_as_int(v), l));
}

// Wave-64 min reduction on the VALU pipe: 4x DPP row_shr + readlane of the
// 4 row minima + scalar mins. Result is wave-uniform.
__device__ __forceinline__ unsigned int wave_redmin_u32(unsigned int x) {
    int t;
    t = __builtin_amdgcn_update_dpp(-1, (int)x, 0x111, 0xF, 0xF, false); // shr:1
    x = uminu(x, (unsigned)t);
    t = __builtin_amdgcn_update_dpp(-1, (int)x, 0x112, 0xF, 0xF, false); // shr:2
    x = uminu(x, (unsigned)t);
    t = __builtin_amdgcn_update_dpp(-1, (int)x, 0x114, 0xF, 0xF, false); // shr:4
    x = uminu(x, (unsigned)t);
    t = __builtin_amdgcn_update_dpp(-1, (int)x, 0x118, 0xF, 0xF, false); // shr:8
    x = uminu(x, (unsigned)t);
    unsigned a = (unsigned)__builtin_amdgcn_readlane((int)x, 15);
    unsigned b = (unsigned)__builtin_amdgcn_readlane((int)x, 31);
    unsigned c = (unsigned)__builtin_amdgcn_readlane((int)x, 47);
    unsigned d = (unsigned)__builtin_amdgcn_readlane((int)x, 63);
    return uminu(uminu(a, b), uminu(c, d));
}

// Per-wave argmin with np.argmin (lowest index on ties) semantics.
__device__ __forceinline__ void wave_argmin_f(float lmin, int lj,
                                              float& mv, int& mj) {
    unsigned u = __float_as_uint(lmin);
    unsigned key = (u & 0x80000000u) ? ~u : (u | 0x80000000u);
    unsigned mk = wave_redmin_u32(key);
    unsigned long long bal = __ballot(key == mk);
    int fl = (int)__builtin_ctzll(bal);
    mj = __builtin_amdgcn_readlane(lj, fl);
    unsigned mu = (mk & 0x80000000u) ? (mk & 0x7FFFFFFFu) : ~mk;
    mv = __uint_as_float(mu);
}

// Same, with a second payload (the winning column's cached pcol value).
__device__ __forceinline__ void wave_argmin_f2(float lmin, int lj, int lpc,
                                               float& mv, int& mj, int& mpc) {
    unsigned u = __float_as_uint(lmin);
    unsigned key = (u & 0x80000000u) ? ~u : (u | 0x80000000u);
    unsigned mk = wave_redmin_u32(key);
    unsigned long long bal = __ballot(key == mk);
    int fl = (int)__builtin_ctzll(bal);
    mj = __builtin_amdgcn_readlane(lj, fl);
    mpc = __builtin_amdgcn_readlane(lpc, fl);
    unsigned mu = (mk & 0x80000000u) ? (mk & 0x7FFFFFFFu) : ~mk;
    mv = __uint_as_float(mu);
}

__global__ __launch_bounds__(THREADS, 1) void match_kernel(
    const float* __restrict__ pred_boxes,    // [NB,NQ,6]
    const float* __restrict__ pred_classes,  // [NB,NQ,NC]
    const float* __restrict__ gt_boxes,      // [NB,NM,6]
    const unsigned int* __restrict__ labels_w,
    const unsigned int* __restrict__ mask_w,
    const unsigned char* __restrict__ mask_b,
    unsigned int* __restrict__ res,          // ws: 64 slots x 4 words
    float* __restrict__ out)
{
    __shared__ float4 pbx4[NQ];          // pred box dims 0..3 (phase-3 use)
    __shared__ float2 pbx2[NQ];          // pred box dims 4..5
    __shared__ float  probT[NC][NQ];     // transposed softmax probs
    __shared__ int    pcol[NQ + 1];      // col -> matched row (1-based), 0=free
    __shared__ int    claim[NQ];         // greedy contention: min row claiming col
    __shared__ int    way_lds[NQ + 1];   // Dijkstra predecessor (no init needed:
                                         // read only for argmin winners, which
                                         // always had a minv-improving write)
    __shared__ float  upot[NM + 1];      // row potentials (1-based)
    __shared__ float4 gb4[NM];
    __shared__ float2 gb2[NM];
    __shared__ int    lab[NM];
    __shared__ int    vpos_s[NM];
    __shared__ int    row2col[NM];
    __shared__ int    rowarg_s[NM];
    __shared__ __align__(16) float rpart_v[4][NM];  // per-wave partials
    __shared__ __align__(16) int   rpart_j[4][NM];
    __shared__ int    ua_s[NM];          // unassigned rows after greedy
    __shared__ int    nua_s;
    __shared__ int    m_sh;
    __shared__ __align__(16) float redv[2][4];   // double-buffered partials
    __shared__ __align__(16) int   redj[2][4];
    __shared__ __align__(16) int   redp[2][4];   // pcol payload
    __shared__ float  redc[4], redb[4];

    const int b = blockIdx.x;
    const int tid = threadIdx.x;
    const int lane = tid & 63;
    const int wv = tid >> 6;

    // ---- Phase 1 (fully overlapped, single barrier at the end):
    //   col-threads: stage own 4 columns global->registers (+LDS copies)
    //   waves 0-2:   LDS init (pcol/claim)
    //   wave 3:      dtype detect -> mask compaction -> gt/label gather
    const bool lv = (tid < NCT);
    const int qb = tid << 2;
    const int qbc = lv ? qb : 0;        // clamped base for LDS reads
#define DECL_COL(s) float cb0_##s = 0.f, cb1_##s = 0.f, cb2_##s = 0.f, \
                          cb3_##s = 0.f, cb4_##s = 0.f, cb5_##s = 0.f;
    S4_LIST(DECL_COL)
    if (lv) {
        const float* cp = pred_classes + ((size_t)b * NQ + qb) * NC;
        const float4 lg0 = *reinterpret_cast<const float4*>(cp + 0);
        const float4 lg1 = *reinterpret_cast<const float4*>(cp + 4);
        const float4 lg2 = *reinterpret_cast<const float4*>(cp + 8);
        const float4 lg3 = *reinterpret_cast<const float4*>(cp + 12);
        float4 r0, r1, r2, r3;           // class-major prob rows for 4 cols
#define SOFTM(LG, C0, C1, C2, C3) { \
        float mx = fmaxf(fmaxf(LG.x, LG.y), fmaxf(LG.z, LG.w)); \
        float e0 = expf(LG.x - mx), e1 = expf(LG.y - mx); \
        float e2 = expf(LG.z - mx), e3 = expf(LG.w - mx); \
        float inv = 1.0f / (e0 + e1 + e2 + e3); \
        C0 = e0 * inv; C1 = e1 * inv; C2 = e2 * inv; C3 = e3 * inv; }
        SOFTM(lg0, r0.x, r1.x, r2.x, r3.x)
        SOFTM(lg1, r0.y, r1.y, r2.y, r3.y)
        SOFTM(lg2, r0.z, r1.z, r2.z, r3.z)
        SOFTM(lg3, r0.w, r1.w, r2.w, r3.w)
        *reinterpret_cast<float4*>(&probT[0][qb]) = r0;
        *reinterpret_cast<float4*>(&probT[1][qb]) = r1;
        *reinterpret_cast<float4*>(&probT[2][qb]) = r2;
        *reinterpret_cast<float4*>(&probT[3][qb]) = r3;
        const float* bp = pred_boxes + ((size_t)b * NQ + qb) * 6;
        const float4 b0 = *reinterpret_cast<const float4*>(bp + 0);
        const float4 b1 = *reinterpret_cast<const float4*>(bp + 4);
        const float4 b2 = *reinterpret_cast<const float4*>(bp + 8);
        const float4 b3 = *reinterpret_cast<const float4*>(bp + 12);
        const float4 b4 = *reinterpret_cast<const float4*>(bp + 16);
        const float4 b5 = *reinterpret_cast<const float4*>(bp + 20);
        cb0_0 = b0.x; cb1_0 = b0.y; cb2_0 = b0.z; cb3_0 = b0.w;
        cb4_0 = b1.x; cb5_0 = b1.y;
        cb0_1 = b1.z; cb1_1 = b1.w; cb2_1 = b2.x; cb3_1 = b2.y;
        cb4_1 = b2.z; cb5_1 = b2.w;
        cb0_2 = b3.x; cb1_2 = b3.y; cb2_2 = b3.z; cb3_2 = b3.w;
        cb4_2 = b4.x; cb5_2 = b4.y;
        cb0_3 = b4.z; cb1_3 = b4.w; cb2_3 = b5.x; cb3_3 = b5.y;
        cb4_3 = b5.z; cb5_3 = b5.w;
#define STORE_PBX(s) { pbx4[qb + (s)] = make_float4(cb0_##s, cb1_##s, \
                           cb2_##s, cb3_##s); \
                       pbx2[qb + (s)] = make_float2(cb4_##s, cb5_##s); }
        S4_LIST(STORE_PBX)
    }
    if (tid < 192) {
        for (int j = tid; j <= NQ; j += 192) pcol[j] = 0;
        for (int j = tid; j < NQ; j += 192) claim[j] = 0x7FFFFFFF;
    }
    if (wv == 3) {
        const int l3 = lane;
        // dtype detect: this wave reads all 1024 words of each buffer
        unsigned labodd = 0u, mgt1 = 0u, modd = 0u;
        #pragma unroll
        for (int k = 0; k < 4; ++k) {
            const uint4 lw4 =
                reinterpret_cast<const uint4*>(labels_w)[l3 * 4 + k];
            labodd |= (lw4.y | lw4.w);
            const uint4 mw4 =
                reinterpret_cast<const uint4*>(mask_w)[l3 * 4 + k];
            mgt1 |= (mw4.x > 1u) | (mw4.y > 1u) | (mw4.z > 1u) | (mw4.w > 1u);
            modd |= (mw4.y | mw4.w);
        }
        const int lmode = __any(labodd != 0u) ? 0 : 1;       // 0=i32,1=i64
        const int mmode = __any(mgt1 != 0u) ? 2
                         : (__any(modd != 0u) ? 0 : 1);      // 2=bytes
        // mask compaction (wave-local ballot over the 64 gt slots)
        int vv;
        if (mmode == 2)      vv = (mask_b[b * NM + l3] != 0);
        else if (mmode == 1) vv = (mask_w[(b * NM + l3) * 2] != 0u);
        else                 vv = (mask_w[b * NM + l3] != 0u);
        unsigned long long bal = __ballot(vv);
        if (vv) {
            int pos = (int)__popcll(bal & ((1ull << l3) - 1ull));
            vpos_s[pos] = l3;
        }
        if (l3 == 0) m_sh = (int)__popcll(bal);
        __builtin_amdgcn_wave_barrier();
        int nw = (int)__popcll(bal);
        if (l3 < nw) {
            int g = vpos_s[l3];
            lab[l3] = (int)(lmode ? labels_w[(size_t)(b * NM + g) * 2]
                                  : labels_w[b * NM + g]);
            const float* gp = gt_boxes + ((size_t)b * NM + g) * 6;
            gb4[l3] = make_float4(gp[0], gp[1], gp[2], gp[3]);
            gb2[l3] = make_float2(gp[4], gp[5]);
        }
    }
    __syncthreads();   // staging + LDS init + matching prep all complete
    const int n = m_sh;

    // cost of slot s vs row data (G4,G2) with prob PRc: bitwise-identical
    // expression to all prior rounds
#define COSTS(s, G4, G2, PRc) \
    (5.0f * (fabsf(cb0_##s - (G4).x) + fabsf(cb1_##s - (G4).y) \
           + fabsf(cb2_##s - (G4).z) + fabsf(cb3_##s - (G4).w) \
           + fabsf(cb4_##s - (G2).x) + fabsf(cb5_##s - (G2).y)) - (PRc))

    // ---- Phase 2a: row reduction, unrolled by 4 to overlap DPP chains ----
    // min-tree slot min + first-equal-slot recovery == sequential
    // strict-< first-min (lowest index on ties).
#define ROWMIN(G4, G2, PR4, MV, MJ) { \
    float c0 = COSTS(0, G4, G2, (PR4).x); \
    float c1 = COSTS(1, G4, G2, (PR4).y); \
    float c2 = COSTS(2, G4, G2, (PR4).z); \
    float c3 = COSTS(3, G4, G2, (PR4).w); \
    float lm = FLT_MAX; int ljj = NQ + 2; \
    if (lv) { \
        lm = fminf(fminf(c0, c1), fminf(c2, c3)); \
        ljj = (c0 == lm) ? qb : ((c1 == lm) ? qb + 1 \
              : ((c2 == lm) ? qb + 2 : qb + 3)); \
    } \
    wave_argmin_f(lm, ljj, MV, MJ); }
    {
        int k = 0;
        for (; k + 3 < n; k += 4) {
            const int lba = lab[k],     lbb = lab[k + 1];
            const int lbc = lab[k + 2], lbd = lab[k + 3];
            const float4 g4a = gb4[k];     const float2 g2a = gb2[k];
            const float4 g4b = gb4[k + 1]; const float2 g2b = gb2[k + 1];
            const float4 g4c = gb4[k + 2]; const float2 g2c = gb2[k + 2];
            const float4 g4d = gb4[k + 3]; const float2 g2d = gb2[k + 3];
            const float4 pra = *reinterpret_cast<const float4*>(&probT[lba][qbc]);
            const float4 prb = *reinterpret_cast<const float4*>(&probT[lbb][qbc]);
            const float4 prc = *reinterpret_cast<const float4*>(&probT[lbc][qbc]);
            const float4 prd = *reinterpret_cast<const float4*>(&probT[lbd][qbc]);
            float mva, mvb, mvc, mvd; int mja, mjb, mjc, mjd;
            ROWMIN(g4a, g2a, pra, mva, mja)
            ROWMIN(g4b, g2b, prb, mvb, mjb)
            ROWMIN(g4c, g2c, prc, mvc, mjc)
            ROWMIN(g4d, g2d, prd, mvd, mjd)
            if (lane == 0) {
                // vectorized partial stores (rows 16B-aligned, k%4==0)
                *reinterpret_cast<float4*>(&rpart_v[wv][k]) =
                    make_float4(mva, mvb, mvc, mvd);
                *reinterpret_cast<int4*>(&rpart_j[wv][k]) =
                    make_int4(mja, mjb, mjc, mjd);
            }
        }
        for (; k < n; ++k) {
            const int lba = lab[k];
            const float4 g4a = gb4[k]; const float2 g2a = gb2[k];
            const float4 pra = *reinterpret_cast<const float4*>(&probT[lba][qbc]);
            float mva; int mja;
            ROWMIN(g4a, g2a, pra, mva, mja)
            if (lane == 0) { rpart_v[wv][k] = mva; rpart_j[wv][k] = mja; }
        }
    }
    __syncthreads();

    // ---- Phase 2b: combine + duals + greedy claim (merged) ----
    if (tid < n) {
        float bv = rpart_v[0][tid]; int bj2 = rpart_j[0][tid];
        #pragma unroll
        for (int w = 1; w < 4; ++w) {
            float vw = rpart_v[w][tid]; int jw = rpart_j[w][tid];
            if (vw < bv || (vw == bv && jw < bj2)) { bv = vw; bj2 = jw; }
        }
        rowarg_s[tid] = bj2;
        upot[tid + 1] = bv;                 // u[i] = row min (dual init)
        atomicMin(&claim[bj2], tid);        // greedy claim, lowest row wins
    }
    if (tid == 0) upot[0] = 0.f;
    __syncthreads();                        // claims + duals final
    if (tid < n) {
        int a = rowarg_s[tid];
        if (claim[a] == tid) pcol[a + 1] = tid + 1;   // unique winner
    }
    if (tid < 64) {
        int un = (lane < n) && (claim[rowarg_s[lane]] != lane);
        unsigned long long bal = __ballot(un);
        if (un) ua_s[(int)__popcll(bal & ((1ull << lane) - 1ull))] = lane;
        if (lane == 0) nua_s = (int)__popcll(bal);
    }
    __syncthreads();                        // pcol winners + ua list visible

    // ---- Phase 2c: shortest augmenting path, 1 barrier per iteration,
    // 1 barrier per stage (stage-exit barrier removed: the augment's inputs
    // are already ordered — way_lds via the final B1, pcol via claim-phase
    // barrier + thread 0's own writes — and the NEXT stage's start barrier
    // orders augment/upot writes against the pc-cache reads).
    {
        float minv_0, minv_1, minv_2, minv_3;
        float vpot_0 = 0.f, vpot_1 = 0.f, vpot_2 = 0.f, vpot_3 = 0.f;
        const int nua = nua_s;

        for (int t = 0; t < nua; ++t) {
            const int i = ua_s[t] + 1;
            __syncthreads();   // stage start: prior augment + upot visible
            minv_0 = FLT_MAX; minv_1 = FLT_MAX;
            minv_2 = FLT_MAX; minv_3 = FLT_MAX;
            unsigned int usedm = 0;
            int intree = 0;
            // cache this stage's pcol for own slots (stage-constant)
            int pc_0 = 0, pc_1 = 0, pc_2 = 0, pc_3 = 0;
            if (lv) {
                pc_0 = pcol[qb + 1]; pc_1 = pcol[qb + 2];
                pc_2 = pcol[qb + 3]; pc_3 = pcol[qb + 4];
            }
            // prefetch start row's data (incl. its prob row)
            int lb = lab[i - 1];
            float base = upot[i];
            float4 g4 = gb4[i - 1];
            float2 g2 = gb2[i - 1];
            float4 pf = *reinterpret_cast<const float4*>(&probT[lb][qbc]);
            int j0 = 0, i0 = i, bj = 0, par = 0;
            while (true) {
                // mark used[j0] (owner thread), add row i0 to the tree
                if (j0 > 0 && ((j0 - 1) >> 2) == tid)
                    usedm |= 1u << ((j0 - 1) & 3);
                if (tid == i0 - 1) intree = 1;
                float lmin = FLT_MAX; int lj = NQ + 2; int lpc = 0;
#define SSCAN(s, PRc) { \
                float cost = COSTS(s, g4, g2, PRc); \
                float cur = cost - base - vpot_##s; \
                if (lv && !((usedm >> (s)) & 1u)) { \
                    if (cur < minv_##s) { minv_##s = cur; \
                                          way_lds[qb + (s) + 1] = j0; } \
                    if (minv_##s < lmin) { lmin = minv_##s; \
                                           lj = qb + (s) + 1; \
                                           lpc = pc_##s; } } }
                SSCAN(0, pf.x) SSCAN(1, pf.y) SSCAN(2, pf.z) SSCAN(3, pf.w)
                float pv; int pj, pp;
                wave_argmin_f2(lmin, lj, lpc, pv, pj, pp);
                if (lane == 0) {
                    redv[par][wv] = pv; redj[par][wv] = pj; redp[par][wv] = pp;
                }
                __syncthreads();   // B1: partials + way_lds visible
                // redundant 4-way combine on every thread
                const float4 rv4 = *reinterpret_cast<const float4*>(redv[par]);
                const int4   rj4 = *reinterpret_cast<const int4*>(redj[par]);
                const int4   rp4 = *reinterpret_cast<const int4*>(redp[par]);
                float dv = rv4.x; int dj = rj4.x; int dp = rp4.x;
                if (rv4.y < dv || (rv4.y == dv && rj4.y < dj)) {
                    dv = rv4.y; dj = rj4.y; dp = rp4.y; }
                if (rv4.z < dv || (rv4.z == dv && rj4.z < dj)) {
                    dv = rv4.z; dj = rj4.z; dp = rp4.z; }
                if (rv4.w < dv || (rv4.w == dv && rj4.w < dj)) {
                    dv = rv4.w; dj = rj4.w; dp = rp4.w; }
                const float delta = dv;
                bj = dj;
                const int nr = dp;      // pcol[bj] via payload (no LDS read)
                // prefetch next row's data early (nr not in tree: no races)
                if (nr != 0) {
                    lb = lab[nr - 1];
                    base = upot[nr];
                    g4 = gb4[nr - 1];
                    g2 = gb2[nr - 1];
                    pf = *reinterpret_cast<const float4*>(&probT[lb][qbc]);
                }
                // v[used] -= delta ; minv[unused] -= delta (local registers)
#define UPDATE(s) { if ((usedm >> (s)) & 1u) vpot_##s -= delta; \
                    else                     minv_##s -= delta; }
                S4_LIST(UPDATE)
                // u[rows in tree] += delta (owner-exclusive LDS update)
                if (intree) upot[tid + 1] += delta;
                if (nr == 0) break;     // bj is a free column
                j0 = bj; i0 = nr; par ^= 1;
            }
            // augment along the alternating path (thread 0, LDS chase).
            // pcol[0] = i is only read by this same chase (jp == 0 case):
            // no cross-thread ordering needed.
            if (tid == 0) {
                pcol[0] = i;
                int jcur = bj;
                while (jcur != 0) {
                    int jp = way_lds[jcur];
                    pcol[jcur] = pcol[jp];
                    jcur = jp;
                }
            }
        }
    }
    __syncthreads();   // final augment visible for phase 3

    // ---- Phase 3: losses over matched pairs (all 256 threads) ----
    // (summation structure unchanged from the verified kernel)
    for (int j = 1 + tid; j <= NQ; j += THREADS) {
        int r = pcol[j];
        if (r > 0) row2col[r - 1] = j - 1;
    }
    __syncthreads();
    float cs = 0.f, bs = 0.f;
    for (int k = tid; k < n; k += THREADS) {
        int q = row2col[k];
        int lb = lab[k];
        cs += -logf(probT[lb][q]);
        float4 p4 = pbx4[q]; float2 p2 = pbx2[q];
        float4 g4 = gb4[k];  float2 g2 = gb2[k];
        bs += fabsf(p4.x - g4.x) + fabsf(p4.y - g4.y) + fabsf(p4.z - g4.z)
            + fabsf(p4.w - g4.w) + fabsf(p2.x - g2.x) + fabsf(p2.y - g2.y);
    }
    for (int off = 32; off > 0; off >>= 1) {
        cs += __shfl_down(cs, off);
        bs += __shfl_down(bs, off);
    }
    {
        int wave = tid >> 6;
        if ((tid & 63) == 0) { redc[wave] = cs; redb[wave] = bs; }
    }
    __syncthreads();

    // ---- Phase 4: publish per-block result; block 0 reduces in-kernel ----
    if (tid == 0) {
        float cls = redc[0] + redc[1] + redc[2] + redc[3];
        float box = redb[0] + redb[1] + redb[2] + redb[3];
        unsigned* slot = res + b * 4;
        __hip_atomic_store(&slot[0], __float_as_uint(cls),
                           __ATOMIC_RELAXED, __HIP_MEMORY_SCOPE_AGENT);
        __hip_atomic_store(&slot[1], __float_as_uint(box),
                           __ATOMIC_RELAXED, __HIP_MEMORY_SCOPE_AGENT);
        __hip_atomic_store(&slot[2], (unsigned)n,
                           __ATOMIC_RELAXED, __HIP_MEMORY_SCOPE_AGENT);
        __hip_atomic_store(&slot[3], MAGIC,
                           __ATOMIC_RELEASE, __HIP_MEMORY_SCOPE_AGENT);
    }
    if (b == 0 && tid < 64) {
        // all 64 blocks are co-resident (64 blocks <= 256 CUs): spin is safe
        unsigned* slot = res + lane * 4;
        while (__hip_atomic_load(&slot[3], __ATOMIC_ACQUIRE,
                                 __HIP_MEMORY_SCOPE_AGENT) != MAGIC) {
            __builtin_amdgcn_s_sleep(1);
        }
        float clsv = __uint_as_float(__hip_atomic_load(
            &slot[0], __ATOMIC_RELAXED, __HIP_MEMORY_SCOPE_AGENT));
        float boxv = __uint_as_float(__hip_atomic_load(
            &slot[1], __ATOMIC_RELAXED, __HIP_MEMORY_SCOPE_AGENT));
        int cntv = (int)__hip_atomic_load(
            &slot[2], __ATOMIC_RELAXED, __HIP_MEMORY_SCOPE_AGENT);
        if (lane == 0) {
            // serial b=0..63 order via readlane: bitwise-identical to the
            // original finalize loop
            float c = 0.f, bx = 0.f;
            int nn = 0;
            for (int bb = 0; bb < 64; ++bb) {
                c += readlane_f(clsv, bb);
                bx += readlane_f(boxv, bb);
                nn += __builtin_amdgcn_readlane(cntv, bb);
            }
            float denom = (nn > 0) ? (float)nn : 1.0f;
            float cl = c / denom;
            float bl = bx / (6.0f * denom);
            out[0] = cl;
            out[1] = bl;
            out[2] = cl + 5.0f * bl;
        }
    }
}

extern "C" void kernel_launch(void* const* d_in, const int* in_sizes, int n_in,
                              void* d_out, int out_size, void* d_ws, size_t ws_size,
                              hipStream_t stream) {
    const float* pred_boxes   = (const float*)d_in[0];
    const float* pred_classes = (const float*)d_in[1];
    const float* gt_boxes     = (const float*)d_in[2];
    const unsigned int*  labels_w = (const unsigned int*)d_in[3];
    const unsigned int*  mask_w   = (const unsigned int*)d_in[4];
    const unsigned char* mask_b   = (const unsigned char*)d_in[4];

    char* ws = (char*)d_ws;
    unsigned* res = (unsigned*)(ws + 16);   // 64 slots x 16B
    float* out = (float*)d_out;

    match_kernel<<<NB, THREADS, 0, stream>>>(pred_boxes, pred_classes, gt_boxes,
                                             labels_w, mask_w, mask_b,
                                             res, out);
}